// Round 6
// baseline (4142.485 us; speedup 1.0000x reference)
//
#include <hip/hip_runtime.h>
#include <math.h>
#include <cstdint>

#define L 2048
#define E 768
#define NH 12
#define NL 4
#define FFN 2048
#define VOC 4096
#define LDQKV (3*E)

typedef unsigned short u16;
typedef __bf16 bf16x8 __attribute__((ext_vector_type(8)));
typedef float f32x4 __attribute__((ext_vector_type(4)));

__device__ __forceinline__ float bf2f(u16 u){
  union { unsigned int i; float f; } v; v.i = ((unsigned int)u) << 16; return v.f;
}
__device__ __forceinline__ u16 f2bf(float f){
  union { float fl; unsigned int i; } v; v.fl = f;
  unsigned int r = v.i + 0x7fffu + ((v.i >> 16) & 1u);
  return (u16)(r >> 16);
}
__device__ __forceinline__ float gelu_exact(float x){
  return 0.5f * x * (1.0f + erff(x * 0.70710678118654752f));
}
// dtype-agnostic raw-input read (f32 world: flag=1; bf16 world: flag=0)
__device__ __forceinline__ float ldw(const void* p, size_t i, int f32w){
  return f32w ? ((const float*)p)[i] : bf2f(((const u16*)p)[i]);
}

#define MFMA_BF16(a,b,c) __builtin_amdgcn_mfma_f32_16x16x32_bf16(a,b,c,0,0,0)

// ---------------- dtype detect ----------------
__global__ __launch_bounds__(256) void detect_kernel(const u16* __restrict__ emb,
                                                     unsigned int* __restrict__ flag){
  __shared__ int s;
  if (threadIdx.x == 0) s = 0;
  __syncthreads();
  float mx = 0.f;
  for (int i = threadIdx.x; i < 16384; i += 256)
    mx = fmaxf(mx, fabsf(bf2f(emb[2*i])));   // f32 data: even u16 = random mantissa bits -> huge
  if (mx > 1e4f) s = 1;                      // benign race: all writers write 1
  __syncthreads();
  if (threadIdx.x == 0) *flag = (unsigned int)s;
}

// ---------------- weight cast -> canonical bf16 (4 elems/thread) ----------------
__global__ __launch_bounds__(256) void cast4_kernel(const void* __restrict__ src,
                                                    u16* __restrict__ dst, int n4,
                                                    const unsigned int* __restrict__ flag){
  int i4 = blockIdx.x * 256 + threadIdx.x;
  if (i4 >= n4) return;
  size_t i = (size_t)i4 * 4;
  ushort4 o;
  if (*flag){
    const float4 f = ((const float4*)src)[i4];
    o.x = f2bf(f.x); o.y = f2bf(f.y); o.z = f2bf(f.z); o.w = f2bf(f.w);
  } else {
    o = ((const ushort4*)src)[i4];
  }
  *(ushort4*)(dst + i) = o;
}

// ---------------- embedding gather -> f32 residual ----------------
__global__ __launch_bounds__(256) void embed_kernel(const int* __restrict__ tok,
                                                    const void* __restrict__ emb,
                                                    const unsigned int* __restrict__ flag,
                                                    float* __restrict__ x){
  const int f32w = (int)*flag;
  int idx = blockIdx.x * 256 + threadIdx.x;      // < L*E
  int l = idx / E, e = idx - l * E;
  x[idx] = ldw(emb, (size_t)tok[l] * E + e, f32w);
}

// ---------------- LayerNorm: f32 in, bf16 out; one wave per row of 768 ----------------
__global__ __launch_bounds__(256) void ln_kernel(const float* __restrict__ x,
                                                 const void* __restrict__ g,
                                                 const void* __restrict__ b,
                                                 size_t goff, size_t boff,
                                                 const unsigned int* __restrict__ flag,
                                                 u16* __restrict__ o){
  const int f32w = (int)*flag;
  const int wave = threadIdx.x >> 6, lane = threadIdx.x & 63;
  const int row = blockIdx.x * 4 + wave;
  const float* xr = x + (size_t)row * E;
  float v[12]; float s = 0.f;
  #pragma unroll
  for (int i = 0; i < 12; i++){ v[i] = xr[lane + i*64]; s += v[i]; }
  #pragma unroll
  for (int off = 32; off > 0; off >>= 1) s += __shfl_xor(s, off);
  const float mean = s * (1.0f / E);
  float vs = 0.f;
  #pragma unroll
  for (int i = 0; i < 12; i++){ float d = v[i] - mean; vs += d * d; }
  #pragma unroll
  for (int off = 32; off > 0; off >>= 1) vs += __shfl_xor(vs, off);
  const float rstd = rsqrtf(vs * (1.0f / E) + 1e-5f);
  u16* orow = o + (size_t)row * E;
  #pragma unroll
  for (int i = 0; i < 12; i++){
    int c = lane + i*64;
    orow[c] = f2bf((v[i] - mean) * rstd * ldw(g, goff + c, f32w) + ldw(b, boff + c, f32w));
  }
}

// ---------------- MFMA GEMM: C[M,N] = A[M,K](bf16) @ B[N,K]^T(bf16) + bias ----------------
// Layout validated (round-4 vs round-5 identity). EPI:
// 0: store bf16 | 1: f32 residual += | 2: f32 gelu store | 3: in-place bf16 *= gelu | 4: final (flag? f32 : bf16)
template<int EPI>
__global__ __launch_bounds__(256)
void gemm_bt(const u16* __restrict__ A, const u16* __restrict__ Bm,
             const void* __restrict__ bias, size_t biasoff,
             const unsigned int* __restrict__ flag,
             u16* __restrict__ outb, float* __restrict__ outf,
             int M, int N, int K){
  __shared__ __align__(16) u16 As[128*32];
  __shared__ __align__(16) u16 Bs[128*32];
  const int t = threadIdx.x;
  const int lane = t & 63;
  const int col = lane & 15, quad = lane >> 4;
  const int wave = t >> 6;
  const int wr = (wave >> 1) * 64, wc = (wave & 1) * 64;
  const int row0 = blockIdx.y * 128, col0 = blockIdx.x * 128;
  const int f32w = (int)*flag;

  const int sr = t >> 2;            // staging: 4 threads/row, 8 elems each
  const int sc = (t & 3) * 8;
  const u16* Ag = A + (size_t)(row0 + sr) * K + sc;
  const u16* Bg = Bm + (size_t)(col0 + sr) * K + sc;
  u16* AsW0 = As + t*8;       u16* AsW1 = As + 2048 + t*8;
  u16* BsW0 = Bs + t*8;       u16* BsW1 = Bs + 2048 + t*8;

  f32x4 acc[4][4];
  #pragma unroll
  for (int i = 0; i < 4; i++)
    #pragma unroll
    for (int j = 0; j < 4; j++) acc[i][j] = (f32x4){0.f,0.f,0.f,0.f};

  for (int k0 = 0; k0 < K; k0 += 32){
    bf16x8 a0 = *(const bf16x8*)(Ag + k0);
    bf16x8 a1 = *(const bf16x8*)(Ag + (size_t)64*K + k0);
    bf16x8 b0 = *(const bf16x8*)(Bg + k0);
    bf16x8 b1 = *(const bf16x8*)(Bg + (size_t)64*K + k0);
    *(bf16x8*)AsW0 = a0;
    *(bf16x8*)AsW1 = a1;
    *(bf16x8*)BsW0 = b0;
    *(bf16x8*)BsW1 = b1;
    __syncthreads();
    bf16x8 af[4], bfr[4];
    #pragma unroll
    for (int i = 0; i < 4; i++)
      af[i] = *(const bf16x8*)(As + (wr + i*16 + col)*32 + quad*8);
    #pragma unroll
    for (int j = 0; j < 4; j++)
      bfr[j] = *(const bf16x8*)(Bs + (wc + j*16 + col)*32 + quad*8);
    #pragma unroll
    for (int i = 0; i < 4; i++)
      #pragma unroll
      for (int j = 0; j < 4; j++)
        acc[i][j] = MFMA_BF16(af[i], bfr[j], acc[i][j]);
    __syncthreads();
  }

  #pragma unroll
  for (int j = 0; j < 4; j++){
    const int c = col0 + wc + j*16 + col;
    const float bb = ldw(bias, biasoff + c, f32w);
    #pragma unroll
    for (int i = 0; i < 4; i++){
      const int r0 = row0 + wr + i*16 + quad*4;
      #pragma unroll
      for (int rr = 0; rr < 4; rr++){
        const float v = acc[i][j][rr] + bb;
        const size_t idx = (size_t)(r0 + rr) * N + c;
        if (EPI == 0)      outb[idx] = f2bf(v);
        else if (EPI == 1) outf[idx] += v;
        else if (EPI == 2) outf[idx] = gelu_exact(v);
        else if (EPI == 3) outb[idx] = f2bf(bf2f(outb[idx]) * gelu_exact(v));
        else { if (f32w) outf[idx] = v; else outb[idx] = f2bf(v); }
      }
    }
  }
}

// ---------------- simple attention with ALiBi; 1 wave = 2 query rows; bf16 out ----------------
__global__ __launch_bounds__(256)
void attn_simple(const u16* __restrict__ qkv, const int* __restrict__ amask,
                 u16* __restrict__ outp){
  const int head = blockIdx.x;
  const int wave = threadIdx.x >> 6, lane = threadIdx.x & 63;
  const int q0 = blockIdx.y * 8 + wave * 2;     // rows q0, q0+1
  __shared__ u16  Ps[4][2][L];                  // bf16 probs (32 KB)
  __shared__ float Qs[4][2][64];
  u16* P0 = Ps[wave][0]; u16* P1 = Ps[wave][1];
  float* Q0 = Qs[wave][0]; float* Q1 = Qs[wave][1];

  // H=12 ALiBi slopes: h<8 -> 2^-(h+1); h>=8 -> 2^-(0.5+(h-8))
  const float slope = exp2f(head < 8 ? -(float)(head+1) : -0.5f - (float)(head-8));

  Q0[lane] = bf2f(qkv[(size_t)(q0  )*LDQKV + head*64 + lane]) * 0.125f;
  Q1[lane] = bf2f(qkv[(size_t)(q0+1)*LDQKV + head*64 + lane]) * 0.125f;
  __syncthreads();

  const u16* kb = qkv + E + head*64;
  float m0 = -1e30f, m1 = -1e30f;
  float sc0[32], sc1[32];
  for (int t = 0; t < 32; t++){
    const int j = t*64 + lane;
    const u16* krow = kb + (size_t)j * LDQKV;
    float d0 = 0.f, d1 = 0.f;
    #pragma unroll
    for (int c = 0; c < 8; c++){
      bf16x8 kv = *(const bf16x8*)(krow + c*8);
      #pragma unroll
      for (int d = 0; d < 8; d++){
        float kf = (float)kv[d];
        d0 = fmaf(Q0[c*8+d], kf, d0);
        d1 = fmaf(Q1[c*8+d], kf, d1);
      }
    }
    const float pad = (amask[j] == 0) ? 1.0f : 0.0f;   // reference adds FLOAT mask
    float s0 = d0 + slope * (float)(j - q0)     + pad;
    float s1 = d1 + slope * (float)(j - (q0+1)) + pad;
    sc0[t] = s0; sc1[t] = s1;
    m0 = fmaxf(m0, s0); m1 = fmaxf(m1, s1);
  }
  #pragma unroll
  for (int off = 32; off > 0; off >>= 1){
    m0 = fmaxf(m0, __shfl_xor(m0, off));
    m1 = fmaxf(m1, __shfl_xor(m1, off));
  }
  float l0 = 0.f, l1 = 0.f;
  for (int t = 0; t < 32; t++){
    const int j = t*64 + lane;
    u16 e0 = f2bf(__expf(sc0[t] - m0));
    u16 e1 = f2bf(__expf(sc1[t] - m1));
    P0[j] = e0; P1[j] = e1;
    l0 += bf2f(e0); l1 += bf2f(e1);
  }
  #pragma unroll
  for (int off = 32; off > 0; off >>= 1){
    l0 += __shfl_xor(l0, off);
    l1 += __shfl_xor(l1, off);
  }
  __syncthreads();

  const u16* vc = qkv + 2*E + head*64 + lane;
  float o0 = 0.f, o1 = 0.f;
  #pragma unroll 8
  for (int j = 0; j < L; j++){
    float vv = bf2f(vc[(size_t)j * LDQKV]);     // coalesced across lanes
    o0 = fmaf(bf2f(P0[j]), vv, o0);             // LDS broadcast
    o1 = fmaf(bf2f(P1[j]), vv, o1);
  }
  outp[(size_t)(q0  )*E + head*64 + lane] = f2bf(o0 / l0);
  outp[(size_t)(q0+1)*E + head*64 + lane] = f2bf(o1 / l1);
}

extern "C" void kernel_launch(void* const* d_in, const int* in_sizes, int n_in,
                              void* d_out, int out_size, void* d_ws, size_t ws_size,
                              hipStream_t stream){
  const int* tokens = (const int*)d_in[0];
  const int* amask  = (const int*)d_in[1];

  // ---- workspace: flag | x f32 | hbuf bf16 | bf16 weight casts  (~73.5 MB; ws >= ~77 MB proven) ----
  unsigned int* flag = (unsigned int*)d_ws;
  float* x   = (float*)((char*)d_ws + 256);           // f32 residual, 6.29 MB
  u16* hbuf  = (u16*)(x + (size_t)L*E);               // LN out bf16, 3.15 MB
  u16* wc    = hbuf + (size_t)L*E;                    // cast weights begin

  const size_t N_INW  = (size_t)NL*3*E*E;   // 7,077,888
  const size_t N_OUTW = (size_t)NL*E*E;     // 2,359,296
  const size_t N_FW1  = (size_t)NL*2*FFN*E; // 12,582,912
  const size_t N_FW2  = (size_t)NL*E*FFN;   // 6,291,456
  const size_t N_MW1  = (size_t)E*E;        //   589,824
  const size_t N_MW2  = (size_t)VOC*E;      // 3,145,728
  u16* in_w  = wc;                 wc += N_INW;
  u16* out_w = wc;                 wc += N_OUTW;
  u16* ffw1  = wc;                 wc += N_FW1;
  u16* ffw2  = wc;                 wc += N_FW2;
  u16* mw1   = wc;                 wc += N_MW1;
  u16* mw2   = wc;                 wc += N_MW2;

  // ---- activations in d_out (high-water 16.8 MB: safe in both dtype worlds) ----
  u16* qkvb  = (u16*)d_out;                          // 9.4 MB   [0, 9.4)
  u16* attnb = (u16*)d_out + (size_t)L*LDQKV;        // 3.15 MB  [9.4, 12.6)  (qkv live, disjoint)
  u16* abuf  = (u16*)d_out;                          // 8.4 MB   (qkv/attn dead)
  float* tbuf = (float*)d_out;                       // 6.3 MB   (abuf dead)

  detect_kernel<<<1, 256, 0, stream>>>((const u16*)d_in[2], flag);
  cast4_kernel<<<(int)(N_INW/1024), 256, 0, stream>>>(d_in[5],  in_w,  (int)(N_INW/4),  flag);
  cast4_kernel<<<(int)(N_OUTW/1024),256, 0, stream>>>(d_in[7],  out_w, (int)(N_OUTW/4), flag);
  cast4_kernel<<<(int)(N_FW1/1024), 256, 0, stream>>>(d_in[11], ffw1,  (int)(N_FW1/4),  flag);
  cast4_kernel<<<(int)(N_FW2/1024), 256, 0, stream>>>(d_in[13], ffw2,  (int)(N_FW2/4),  flag);
  cast4_kernel<<<(int)(N_MW1/1024), 256, 0, stream>>>(d_in[17], mw1,   (int)(N_MW1/4),  flag);
  cast4_kernel<<<(int)(N_MW2/1024), 256, 0, stream>>>(d_in[21], mw2,   (int)(N_MW2/4),  flag);

  embed_kernel<<<L*E/256, 256, 0, stream>>>(tokens, d_in[2], flag, x);

  for (int ly = 0; ly < NL; ly++){
    ln_kernel<<<L/4, 256, 0, stream>>>(x, d_in[3], d_in[4],
        (size_t)ly*E, (size_t)ly*E, flag, hbuf);
    gemm_bt<0><<<dim3(3*E/128, L/128), 256, 0, stream>>>(hbuf, in_w + (size_t)ly*3*E*E,
        d_in[6], (size_t)ly*3*E, flag, qkvb, nullptr, L, 3*E, E);
    attn_simple<<<dim3(NH, L/8), 256, 0, stream>>>(qkvb, amask, attnb);
    gemm_bt<1><<<dim3(E/128, L/128), 256, 0, stream>>>(attnb, out_w + (size_t)ly*E*E,
        d_in[8], (size_t)ly*E, flag, nullptr, x, L, E, E);
    ln_kernel<<<L/4, 256, 0, stream>>>(x, d_in[9], d_in[10],
        (size_t)ly*E, (size_t)ly*E, flag, hbuf);
    gemm_bt<0><<<dim3(FFN/128, L/128), 256, 0, stream>>>(hbuf,
        ffw1 + (size_t)ly*2*FFN*E, d_in[12], (size_t)ly*2*FFN, flag,
        abuf, nullptr, L, FFN, E);
    gemm_bt<3><<<dim3(FFN/128, L/128), 256, 0, stream>>>(hbuf,
        ffw1 + (size_t)ly*2*FFN*E + (size_t)FFN*E, d_in[12], (size_t)ly*2*FFN + FFN, flag,
        abuf, nullptr, L, FFN, E);
    gemm_bt<1><<<dim3(E/128, L/128), 256, 0, stream>>>(abuf, ffw2 + (size_t)ly*E*FFN,
        d_in[14], (size_t)ly*E, flag, nullptr, x, L, E, FFN);
  }
  ln_kernel<<<L/4, 256, 0, stream>>>(x, d_in[15], d_in[16], 0, 0, flag, hbuf);
  gemm_bt<2><<<dim3(E/128, L/128), 256, 0, stream>>>(hbuf, mw1,
      d_in[18], 0, flag, nullptr, tbuf, L, E, E);
  ln_kernel<<<L/4, 256, 0, stream>>>(tbuf, d_in[19], d_in[20], 0, 0, flag, hbuf);
  gemm_bt<4><<<dim3(VOC/128, L/128), 256, 0, stream>>>(hbuf, mw2,
      d_in[22], 0, flag, (u16*)d_out, (float*)d_out, L, VOC, E);
}

// Round 7
// 1586.444 us; speedup vs baseline: 2.6112x; 2.6112x over previous
//
#include <hip/hip_runtime.h>
#include <math.h>
#include <cstdint>

#define L 2048
#define E 768
#define NH 12
#define NL 4
#define FFN 2048
#define VOC 4096
#define LDQKV (3*E)

typedef unsigned short u16;
typedef __bf16 bf16x8 __attribute__((ext_vector_type(8)));
typedef float f32x4 __attribute__((ext_vector_type(4)));

__device__ __forceinline__ float bf2f(u16 u){
  union { unsigned int i; float f; } v; v.i = ((unsigned int)u) << 16; return v.f;
}
__device__ __forceinline__ u16 f2bf(float f){
  union { float fl; unsigned int i; } v; v.fl = f;
  unsigned int r = v.i + 0x7fffu + ((v.i >> 16) & 1u);
  return (u16)(r >> 16);
}
__device__ __forceinline__ float gelu_exact(float x){
  return 0.5f * x * (1.0f + erff(x * 0.70710678118654752f));
}
// dtype-agnostic raw-input read (f32 world: flag=1; bf16 world: flag=0)
__device__ __forceinline__ float ldw(const void* p, size_t i, int f32w){
  return f32w ? ((const float*)p)[i] : bf2f(((const u16*)p)[i]);
}

#define MFMA_BF16(a,b,c) __builtin_amdgcn_mfma_f32_16x16x32_bf16(a,b,c,0,0,0)

// ---------------- dtype detect ----------------
__global__ __launch_bounds__(256) void detect_kernel(const u16* __restrict__ emb,
                                                     unsigned int* __restrict__ flag){
  __shared__ int s;
  if (threadIdx.x == 0) s = 0;
  __syncthreads();
  float mx = 0.f;
  for (int i = threadIdx.x; i < 16384; i += 256)
    mx = fmaxf(mx, fabsf(bf2f(emb[2*i])));   // f32 data: even u16 = random mantissa bits -> huge
  if (mx > 1e4f) s = 1;                      // benign race: all writers write 1
  __syncthreads();
  if (threadIdx.x == 0) *flag = (unsigned int)s;
}

// ---------------- weight cast -> canonical bf16 (4 elems/thread) ----------------
__global__ __launch_bounds__(256) void cast4_kernel(const void* __restrict__ src,
                                                    u16* __restrict__ dst, int n4,
                                                    const unsigned int* __restrict__ flag){
  int i4 = blockIdx.x * 256 + threadIdx.x;
  if (i4 >= n4) return;
  size_t i = (size_t)i4 * 4;
  ushort4 o;
  if (*flag){
    const float4 f = ((const float4*)src)[i4];
    o.x = f2bf(f.x); o.y = f2bf(f.y); o.z = f2bf(f.z); o.w = f2bf(f.w);
  } else {
    o = ((const ushort4*)src)[i4];
  }
  *(ushort4*)(dst + i) = o;
}

// ---------------- embedding gather -> f32 residual ----------------
__global__ __launch_bounds__(256) void embed_kernel(const int* __restrict__ tok,
                                                    const void* __restrict__ emb,
                                                    const unsigned int* __restrict__ flag,
                                                    float* __restrict__ x){
  const int f32w = (int)*flag;
  int idx = blockIdx.x * 256 + threadIdx.x;      // < L*E
  int l = idx / E, e = idx - l * E;
  x[idx] = ldw(emb, (size_t)tok[l] * E + e, f32w);
}

// ---------------- LayerNorm: f32 in, bf16 out; one wave per row of 768 ----------------
__global__ __launch_bounds__(256) void ln_kernel(const float* __restrict__ x,
                                                 const void* __restrict__ g,
                                                 const void* __restrict__ b,
                                                 size_t goff, size_t boff,
                                                 const unsigned int* __restrict__ flag,
                                                 u16* __restrict__ o){
  const int f32w = (int)*flag;
  const int wave = threadIdx.x >> 6, lane = threadIdx.x & 63;
  const int row = blockIdx.x * 4 + wave;
  const float* xr = x + (size_t)row * E;
  float v[12]; float s = 0.f;
  #pragma unroll
  for (int i = 0; i < 12; i++){ v[i] = xr[lane + i*64]; s += v[i]; }
  #pragma unroll
  for (int off = 32; off > 0; off >>= 1) s += __shfl_xor(s, off);
  const float mean = s * (1.0f / E);
  float vs = 0.f;
  #pragma unroll
  for (int i = 0; i < 12; i++){ float d = v[i] - mean; vs += d * d; }
  #pragma unroll
  for (int off = 32; off > 0; off >>= 1) vs += __shfl_xor(vs, off);
  const float rstd = rsqrtf(vs * (1.0f / E) + 1e-5f);
  u16* orow = o + (size_t)row * E;
  #pragma unroll
  for (int i = 0; i < 12; i++){
    int c = lane + i*64;
    orow[c] = f2bf((v[i] - mean) * rstd * ldw(g, goff + c, f32w) + ldw(b, boff + c, f32w));
  }
}

// ---------------- MFMA GEMM: C[M,N] = A[M,K](bf16) @ B[N,K]^T(bf16) + bias ----------------
// Layouts validated end-to-end (round 4/5 identity + round-6 pass). EPI:
// 0: store bf16 | 1: f32 residual += | 2: f32 gelu store | 3: in-place bf16 *= gelu | 4: final (flag? f32 : bf16)
template<int EPI>
__global__ __launch_bounds__(256)
void gemm_bt(const u16* __restrict__ A, const u16* __restrict__ Bm,
             const void* __restrict__ bias, size_t biasoff,
             const unsigned int* __restrict__ flag,
             u16* __restrict__ outb, float* __restrict__ outf,
             int M, int N, int K){
  __shared__ __align__(16) u16 As[128*32];
  __shared__ __align__(16) u16 Bs[128*32];
  const int t = threadIdx.x;
  const int lane = t & 63;
  const int col = lane & 15, quad = lane >> 4;
  const int wave = t >> 6;
  const int wr = (wave >> 1) * 64, wc = (wave & 1) * 64;
  const int row0 = blockIdx.y * 128, col0 = blockIdx.x * 128;
  const int f32w = (int)*flag;

  const int sr = t >> 2;            // staging: 4 threads/row, 8 elems each
  const int sc = (t & 3) * 8;
  const u16* Ag = A + (size_t)(row0 + sr) * K + sc;
  const u16* Bg = Bm + (size_t)(col0 + sr) * K + sc;
  u16* AsW0 = As + t*8;       u16* AsW1 = As + 2048 + t*8;
  u16* BsW0 = Bs + t*8;       u16* BsW1 = Bs + 2048 + t*8;

  f32x4 acc[4][4];
  #pragma unroll
  for (int i = 0; i < 4; i++)
    #pragma unroll
    for (int j = 0; j < 4; j++) acc[i][j] = (f32x4){0.f,0.f,0.f,0.f};

  for (int k0 = 0; k0 < K; k0 += 32){
    bf16x8 a0 = *(const bf16x8*)(Ag + k0);
    bf16x8 a1 = *(const bf16x8*)(Ag + (size_t)64*K + k0);
    bf16x8 b0 = *(const bf16x8*)(Bg + k0);
    bf16x8 b1 = *(const bf16x8*)(Bg + (size_t)64*K + k0);
    *(bf16x8*)AsW0 = a0;
    *(bf16x8*)AsW1 = a1;
    *(bf16x8*)BsW0 = b0;
    *(bf16x8*)BsW1 = b1;
    __syncthreads();
    bf16x8 af[4], bfr[4];
    #pragma unroll
    for (int i = 0; i < 4; i++)
      af[i] = *(const bf16x8*)(As + (wr + i*16 + col)*32 + quad*8);
    #pragma unroll
    for (int j = 0; j < 4; j++)
      bfr[j] = *(const bf16x8*)(Bs + (wc + j*16 + col)*32 + quad*8);
    #pragma unroll
    for (int i = 0; i < 4; i++)
      #pragma unroll
      for (int j = 0; j < 4; j++)
        acc[i][j] = MFMA_BF16(af[i], bfr[j], acc[i][j]);
    __syncthreads();
  }

  #pragma unroll
  for (int j = 0; j < 4; j++){
    const int c = col0 + wc + j*16 + col;
    const float bb = ldw(bias, biasoff + c, f32w);
    #pragma unroll
    for (int i = 0; i < 4; i++){
      const int r0 = row0 + wr + i*16 + quad*4;
      #pragma unroll
      for (int rr = 0; rr < 4; rr++){
        const float v = acc[i][j][rr] + bb;
        const size_t idx = (size_t)(r0 + rr) * N + c;
        if (EPI == 0)      outb[idx] = f2bf(v);
        else if (EPI == 1) outf[idx] += v;
        else if (EPI == 2) outf[idx] = gelu_exact(v);
        else if (EPI == 3) outb[idx] = f2bf(bf2f(outb[idx]) * gelu_exact(v));
        else { if (f32w) outf[idx] = v; else outb[idx] = f2bf(v); }
      }
    }
  }
}

// ---------------- V transpose: Vt[h][d][j] = qkv[j*LDQKV + 2E + h*64 + d] ----------------
// grid (NH, L/32); thread: d = t&63 (coalesced reads), j-octet = (t>>6)*8 (b128 writes)
__global__ __launch_bounds__(256)
void vt_kernel(const u16* __restrict__ qkv, u16* __restrict__ Vt){
  const int h = blockIdx.x;
  const int t = threadIdx.x;
  const int d = t & 63;
  const int j0 = blockIdx.y * 32 + (t >> 6) * 8;
  u16 tmp[8];
  #pragma unroll
  for (int jj = 0; jj < 8; jj++)
    tmp[jj] = qkv[(size_t)(j0 + jj) * LDQKV + 2*E + h*64 + d];
  *(ushort4*)(Vt + (size_t)(h*64 + d) * L + j0)     = *(ushort4*)(tmp);
  *(ushort4*)(Vt + (size_t)(h*64 + d) * L + j0 + 4) = *(ushort4*)(tmp + 4);
}

// ---------------- MFMA flash attention with ALiBi; 1 wave = 16 Q rows ----------------
// Fragment roles identical to validated gemm_bt: A m=lane&15,k=quad*8+j; B n=lane&15;
// C/D row=quad*4+reg, col=lane&15.
__global__ __launch_bounds__(256)
void attn_mfma(const u16* __restrict__ qkv, const u16* __restrict__ Vt,
               const int* __restrict__ amask, u16* __restrict__ outp){
  const int head = blockIdx.x;
  const int wave = threadIdx.x >> 6, lane = threadIdx.x & 63;
  const int col = lane & 15, quad = lane >> 4;
  const int q0 = blockIdx.y * 64 + wave * 16;

  // per-wave P buffer: 16 rows x pitch 40 u16 (16B-aligned rows, ~4-way write conflicts max)
  __shared__ __align__(16) u16 Pb[4][16*40];
  u16* P = Pb[wave];

  // H=12 ALiBi slopes: h<8 -> 2^-(h+1); h>=8 -> 2^-(0.5+(h-8))
  const float slope = exp2f(head < 8 ? -(float)(head+1) : -0.5f - (float)(head-8));
  const float scale = 0.125f;     // 1/sqrt(64)

  const u16* qrow = qkv + (size_t)(q0 + col) * LDQKV + head*64;
  const bf16x8 qf0 = *(const bf16x8*)(qrow + quad*8);
  const bf16x8 qf1 = *(const bf16x8*)(qrow + 32 + quad*8);

  const u16* kbase  = qkv + E + head*64;
  const u16* vtbase = Vt + (size_t)(head*64) * L;

  float m_i[4] = {-1e30f,-1e30f,-1e30f,-1e30f};
  float l_i[4] = {0.f,0.f,0.f,0.f};
  f32x4 oacc[4];
  #pragma unroll
  for (int nt = 0; nt < 4; nt++) oacc[nt] = (f32x4){0.f,0.f,0.f,0.f};

  for (int kt = 0; kt < L; kt += 32){
    // ---- QK^T: S[16q][32k] via 4 MFMAs ----
    f32x4 s[2];
    #pragma unroll
    for (int nt = 0; nt < 2; nt++){
      const u16* krow = kbase + (size_t)(kt + nt*16 + col) * LDQKV;
      bf16x8 kf0 = *(const bf16x8*)(krow + quad*8);
      bf16x8 kf1 = *(const bf16x8*)(krow + 32 + quad*8);
      f32x4 z = (f32x4){0.f,0.f,0.f,0.f};
      z = MFMA_BF16(qf0, kf0, z);
      z = MFMA_BF16(qf1, kf1, z);
      s[nt] = z;
    }
    // ---- online softmax over the 32-key tile ----
    const int j0 = kt + col, j1 = kt + 16 + col;
    const float pad0 = (amask[j0] == 0) ? 1.0f : 0.0f;   // reference adds FLOAT mask
    const float pad1 = (amask[j1] == 0) ? 1.0f : 0.0f;
    float al[4];
    #pragma unroll
    for (int r = 0; r < 4; r++){
      const float ip = (float)(q0 + quad*4 + r);
      float s0 = s[0][r] * scale + slope * ((float)j0 - ip) + pad0;
      float s1 = s[1][r] * scale + slope * ((float)j1 - ip) + pad1;
      float mx = fmaxf(s0, s1);
      mx = fmaxf(mx, __shfl_xor(mx, 1));
      mx = fmaxf(mx, __shfl_xor(mx, 2));
      mx = fmaxf(mx, __shfl_xor(mx, 4));
      mx = fmaxf(mx, __shfl_xor(mx, 8));
      const float mnew = fmaxf(m_i[r], mx);
      const float a = __expf(m_i[r] - mnew);
      m_i[r] = mnew; al[r] = a;
      u16 p0 = f2bf(__expf(s0 - mnew));
      u16 p1 = f2bf(__expf(s1 - mnew));
      P[(quad*4 + r)*40 + col]      = p0;
      P[(quad*4 + r)*40 + 16 + col] = p1;
      float ps = bf2f(p0) + bf2f(p1);           // sum what PV will actually use
      ps += __shfl_xor(ps, 1);
      ps += __shfl_xor(ps, 2);
      ps += __shfl_xor(ps, 4);
      ps += __shfl_xor(ps, 8);
      l_i[r] = l_i[r] * a + ps;
    }
    #pragma unroll
    for (int nt = 0; nt < 4; nt++)
      #pragma unroll
      for (int r = 0; r < 4; r++) oacc[nt][r] *= al[r];

    // ---- PV: O[16q][64d] += P[16x32] @ V[32x64] via 4 MFMAs ----
    asm volatile("s_waitcnt lgkmcnt(0)" ::: "memory");
    const bf16x8 pa = *(const bf16x8*)(P + col*40 + quad*8);  // A[m=q(col)][k=quad*8+j]
    #pragma unroll
    for (int nt = 0; nt < 4; nt++){
      const bf16x8 vb = *(const bf16x8*)(vtbase + (size_t)(nt*16 + col) * L + kt + quad*8);
      oacc[nt] = MFMA_BF16(pa, vb, oacc[nt]);
    }
  }
  #pragma unroll
  for (int nt = 0; nt < 4; nt++)
    #pragma unroll
    for (int r = 0; r < 4; r++){
      const int row = q0 + quad*4 + r;
      outp[(size_t)row * E + head*64 + nt*16 + col] = f2bf(oacc[nt][r] / l_i[r]);
    }
}

extern "C" void kernel_launch(void* const* d_in, const int* in_sizes, int n_in,
                              void* d_out, int out_size, void* d_ws, size_t ws_size,
                              hipStream_t stream){
  const int* tokens = (const int*)d_in[0];
  const int* amask  = (const int*)d_in[1];

  // ---- workspace: flag | x f32 | hbuf bf16 | Vt bf16 | bf16 weight casts (~76.7 MB) ----
  unsigned int* flag = (unsigned int*)d_ws;
  float* x   = (float*)((char*)d_ws + 256);           // f32 residual, 6.29 MB
  u16* hbuf  = (u16*)(x + (size_t)L*E);               // LN out bf16, 3.15 MB
  u16* vtb   = hbuf + (size_t)L*E;                    // V^T [NH][64][L], 3.15 MB
  u16* wc    = vtb + (size_t)NH*64*L;                 // cast weights begin

  const size_t N_INW  = (size_t)NL*3*E*E;
  const size_t N_OUTW = (size_t)NL*E*E;
  const size_t N_FW1  = (size_t)NL*2*FFN*E;
  const size_t N_FW2  = (size_t)NL*E*FFN;
  const size_t N_MW1  = (size_t)E*E;
  const size_t N_MW2  = (size_t)VOC*E;
  u16* in_w  = wc;                 wc += N_INW;
  u16* out_w = wc;                 wc += N_OUTW;
  u16* ffw1  = wc;                 wc += N_FW1;
  u16* ffw2  = wc;                 wc += N_FW2;
  u16* mw1   = wc;                 wc += N_MW1;
  u16* mw2   = wc;                 wc += N_MW2;

  // ---- activations in d_out (high-water 16.8 MB) ----
  u16* qkvb  = (u16*)d_out;                          // 9.4 MB   [0, 9.4)
  u16* attnb = (u16*)d_out + (size_t)L*LDQKV;        // 3.15 MB  [9.4, 12.6)
  u16* abuf  = (u16*)d_out;                          // 8.4 MB   (qkv/attn dead)
  float* tbuf = (float*)d_out;                       // 6.3 MB   (abuf dead)

  detect_kernel<<<1, 256, 0, stream>>>((const u16*)d_in[2], flag);
  cast4_kernel<<<(int)(N_INW/1024), 256, 0, stream>>>(d_in[5],  in_w,  (int)(N_INW/4),  flag);
  cast4_kernel<<<(int)(N_OUTW/1024),256, 0, stream>>>(d_in[7],  out_w, (int)(N_OUTW/4), flag);
  cast4_kernel<<<(int)(N_FW1/1024), 256, 0, stream>>>(d_in[11], ffw1,  (int)(N_FW1/4),  flag);
  cast4_kernel<<<(int)(N_FW2/1024), 256, 0, stream>>>(d_in[13], ffw2,  (int)(N_FW2/4),  flag);
  cast4_kernel<<<(int)(N_MW1/1024), 256, 0, stream>>>(d_in[17], mw1,   (int)(N_MW1/4),  flag);
  cast4_kernel<<<(int)(N_MW2/1024), 256, 0, stream>>>(d_in[21], mw2,   (int)(N_MW2/4),  flag);

  embed_kernel<<<L*E/256, 256, 0, stream>>>(tokens, d_in[2], flag, x);

  for (int ly = 0; ly < NL; ly++){
    ln_kernel<<<L/4, 256, 0, stream>>>(x, d_in[3], d_in[4],
        (size_t)ly*E, (size_t)ly*E, flag, hbuf);
    gemm_bt<0><<<dim3(3*E/128, L/128), 256, 0, stream>>>(hbuf, in_w + (size_t)ly*3*E*E,
        d_in[6], (size_t)ly*3*E, flag, qkvb, nullptr, L, 3*E, E);
    vt_kernel<<<dim3(NH, L/32), 256, 0, stream>>>(qkvb, vtb);
    attn_mfma<<<dim3(NH, L/64), 256, 0, stream>>>(qkvb, vtb, amask, attnb);
    gemm_bt<1><<<dim3(E/128, L/128), 256, 0, stream>>>(attnb, out_w + (size_t)ly*E*E,
        d_in[8], (size_t)ly*E, flag, nullptr, x, L, E, E);
    ln_kernel<<<L/4, 256, 0, stream>>>(x, d_in[9], d_in[10],
        (size_t)ly*E, (size_t)ly*E, flag, hbuf);
    gemm_bt<0><<<dim3(FFN/128, L/128), 256, 0, stream>>>(hbuf,
        ffw1 + (size_t)ly*2*FFN*E, d_in[12], (size_t)ly*2*FFN, flag,
        abuf, nullptr, L, FFN, E);
    gemm_bt<3><<<dim3(FFN/128, L/128), 256, 0, stream>>>(hbuf,
        ffw1 + (size_t)ly*2*FFN*E + (size_t)FFN*E, d_in[12], (size_t)ly*2*FFN + FFN, flag,
        abuf, nullptr, L, FFN, E);
    gemm_bt<1><<<dim3(E/128, L/128), 256, 0, stream>>>(abuf, ffw2 + (size_t)ly*E*FFN,
        d_in[14], (size_t)ly*E, flag, nullptr, x, L, E, FFN);
  }
  ln_kernel<<<L/4, 256, 0, stream>>>(x, d_in[15], d_in[16], 0, 0, flag, hbuf);
  gemm_bt<2><<<dim3(E/128, L/128), 256, 0, stream>>>(hbuf, mw1,
      d_in[18], 0, flag, nullptr, tbuf, L, E, E);
  ln_kernel<<<L/4, 256, 0, stream>>>(tbuf, d_in[19], d_in[20], 0, 0, flag, hbuf);
  gemm_bt<4><<<dim3(VOC/128, L/128), 256, 0, stream>>>(hbuf, mw2,
      d_in[22], 0, flag, (u16*)d_out, (float*)d_out, L, VOC, E);
}

// Round 8
// 1229.244 us; speedup vs baseline: 3.3699x; 1.2906x over previous
//
#include <hip/hip_runtime.h>
#include <math.h>
#include <cstdint>

#define L 2048
#define E 768
#define NH 12
#define NL 4
#define FFN 2048
#define VOC 4096
#define LDQKV (3*E)

typedef unsigned short u16;
typedef __bf16 bf16x8 __attribute__((ext_vector_type(8)));
typedef float f32x4 __attribute__((ext_vector_type(4)));

__device__ __forceinline__ float bf2f(u16 u){
  union { unsigned int i; float f; } v; v.i = ((unsigned int)u) << 16; return v.f;
}
__device__ __forceinline__ u16 f2bf(float f){
  union { float fl; unsigned int i; } v; v.fl = f;
  unsigned int r = v.i + 0x7fffu + ((v.i >> 16) & 1u);
  return (u16)(r >> 16);
}
__device__ __forceinline__ float gelu_exact(float x){
  return 0.5f * x * (1.0f + erff(x * 0.70710678118654752f));
}
__device__ __forceinline__ float ldw(const void* p, size_t i, int f32w){
  return f32w ? ((const float*)p)[i] : bf2f(((const u16*)p)[i]);
}

#define MFMA_BF16(a,b,c) __builtin_amdgcn_mfma_f32_16x16x32_bf16(a,b,c,0,0,0)

// async global->LDS, 16B/lane; LDS dest = wave-uniform base + lane*16 (m97/m104)
__device__ __forceinline__ void gload16(const u16* g, const u16* l){
  __builtin_amdgcn_global_load_lds(
      (__attribute__((address_space(1))) void*)(uintptr_t)(const void*)g,
      (__attribute__((address_space(3))) void*)(unsigned int)(uintptr_t)(const void*)l,
      16, 0, 0);
}

// ---------------- dtype detect ----------------
__global__ __launch_bounds__(256) void detect_kernel(const u16* __restrict__ emb,
                                                     unsigned int* __restrict__ flag){
  __shared__ int s;
  if (threadIdx.x == 0) s = 0;
  __syncthreads();
  float mx = 0.f;
  for (int i = threadIdx.x; i < 16384; i += 256)
    mx = fmaxf(mx, fabsf(bf2f(emb[2*i])));
  if (mx > 1e4f) s = 1;
  __syncthreads();
  if (threadIdx.x == 0) *flag = (unsigned int)s;
}

// ---------------- weight cast -> canonical bf16 ----------------
__global__ __launch_bounds__(256) void cast4_kernel(const void* __restrict__ src,
                                                    u16* __restrict__ dst, int n4,
                                                    const unsigned int* __restrict__ flag){
  int i4 = blockIdx.x * 256 + threadIdx.x;
  if (i4 >= n4) return;
  size_t i = (size_t)i4 * 4;
  ushort4 o;
  if (*flag){
    const float4 f = ((const float4*)src)[i4];
    o.x = f2bf(f.x); o.y = f2bf(f.y); o.z = f2bf(f.z); o.w = f2bf(f.w);
  } else {
    o = ((const ushort4*)src)[i4];
  }
  *(ushort4*)(dst + i) = o;
}

// ---------------- key-pad float mask precompute ----------------
__global__ __launch_bounds__(256) void padf_kernel(const int* __restrict__ amask,
                                                   float* __restrict__ padf){
  int i = blockIdx.x * 256 + threadIdx.x;
  padf[i] = (amask[i] == 0) ? 1.0f : 0.0f;   // reference adds FLOAT mask
}

// ---------------- embedding gather -> f32 residual ----------------
__global__ __launch_bounds__(256) void embed_kernel(const int* __restrict__ tok,
                                                    const void* __restrict__ emb,
                                                    const unsigned int* __restrict__ flag,
                                                    float* __restrict__ x){
  const int f32w = (int)*flag;
  int idx = blockIdx.x * 256 + threadIdx.x;
  int l = idx / E, e = idx - l * E;
  x[idx] = ldw(emb, (size_t)tok[l] * E + e, f32w);
}

// ---------------- LayerNorm: f32 in, bf16 out ----------------
__global__ __launch_bounds__(256) void ln_kernel(const float* __restrict__ x,
                                                 const void* __restrict__ g,
                                                 const void* __restrict__ b,
                                                 size_t goff, size_t boff,
                                                 const unsigned int* __restrict__ flag,
                                                 u16* __restrict__ o){
  const int f32w = (int)*flag;
  const int wave = threadIdx.x >> 6, lane = threadIdx.x & 63;
  const int row = blockIdx.x * 4 + wave;
  const float* xr = x + (size_t)row * E;
  float v[12]; float s = 0.f;
  #pragma unroll
  for (int i = 0; i < 12; i++){ v[i] = xr[lane + i*64]; s += v[i]; }
  #pragma unroll
  for (int off = 32; off > 0; off >>= 1) s += __shfl_xor(s, off);
  const float mean = s * (1.0f / E);
  float vs = 0.f;
  #pragma unroll
  for (int i = 0; i < 12; i++){ float d = v[i] - mean; vs += d * d; }
  #pragma unroll
  for (int off = 32; off > 0; off >>= 1) vs += __shfl_xor(vs, off);
  const float rstd = rsqrtf(vs * (1.0f / E) + 1e-5f);
  u16* orow = o + (size_t)row * E;
  #pragma unroll
  for (int i = 0; i < 12; i++){
    int c = lane + i*64;
    orow[c] = f2bf((v[i] - mean) * rstd * ldw(g, goff + c, f32w) + ldw(b, boff + c, f32w));
  }
}

// ---------------- MFMA GEMM with async LDS staging (m97 pattern) ----------------
// C[M,N] = A[M,K](bf16) @ B[N,K]^T(bf16) + bias. gridDim.z>1 => split-K (EPI 1 only).
// EPI 0: bf16 store | 1: f32 atomicAdd residual | 2: f32 gelu | 3: bf16 in-place *= gelu | 4: final (flag? f32 : bf16)
template<int EPI>
__global__ __launch_bounds__(256)
void gemm_bt(const u16* __restrict__ A, const u16* __restrict__ Bm,
             const void* __restrict__ bias, size_t biasoff,
             const unsigned int* __restrict__ flag,
             u16* __restrict__ outb, float* __restrict__ outf,
             int M, int N, int K){
  __shared__ __align__(16) u16 As[128*32];
  __shared__ __align__(16) u16 Bs[128*32];
  const int t = threadIdx.x;
  const int lane = t & 63;
  const int col = lane & 15, quad = lane >> 4;
  const int wave = t >> 6;
  const int wr = (wave >> 1) * 64, wc = (wave & 1) * 64;
  const int row0 = blockIdx.y * 128, col0 = blockIdx.x * 128;
  const int f32w = (int)*flag;

  int kb = 0, ke = K;
  if (gridDim.z > 1){ const int kc = K / (int)gridDim.z; kb = blockIdx.z * kc; ke = kb + kc; }

  const int sr = t >> 2;            // staging map: 4 lanes/row, 8 u16 (16B) each
  const int sc = (t & 3) * 8;
  const u16* Ag = A + (size_t)(row0 + sr) * K + sc;
  const u16* Bg = Bm + (size_t)(col0 + sr) * K + sc;
  const u16* AsD = As + wave * 512;   // wave-uniform LDS dest (+ lane*16B implicit)
  const u16* BsD = Bs + wave * 512;

  f32x4 acc[4][4];
  #pragma unroll
  for (int i = 0; i < 4; i++)
    #pragma unroll
    for (int j = 0; j < 4; j++) acc[i][j] = (f32x4){0.f,0.f,0.f,0.f};

  for (int k0 = kb; k0 < ke; k0 += 32){
    gload16(Ag + k0,               AsD);
    gload16(Ag + (size_t)64*K + k0, AsD + 64*32);
    gload16(Bg + k0,               BsD);
    gload16(Bg + (size_t)64*K + k0, BsD + 64*32);
    __syncthreads();                 // drains vmcnt(0): staged data visible
    bf16x8 af[4], bfr[4];
    #pragma unroll
    for (int i = 0; i < 4; i++)
      af[i] = *(const bf16x8*)(As + (wr + i*16 + col)*32 + quad*8);
    #pragma unroll
    for (int j = 0; j < 4; j++)
      bfr[j] = *(const bf16x8*)(Bs + (wc + j*16 + col)*32 + quad*8);
    #pragma unroll
    for (int i = 0; i < 4; i++)
      #pragma unroll
      for (int j = 0; j < 4; j++)
        acc[i][j] = MFMA_BF16(af[i], bfr[j], acc[i][j]);
    __syncthreads();
  }

  #pragma unroll
  for (int j = 0; j < 4; j++){
    const int c = col0 + wc + j*16 + col;
    const float bb = (gridDim.z > 1 && blockIdx.z != 0) ? 0.f : ldw(bias, biasoff + c, f32w);
    #pragma unroll
    for (int i = 0; i < 4; i++){
      const int r0 = row0 + wr + i*16 + quad*4;
      #pragma unroll
      for (int rr = 0; rr < 4; rr++){
        const float v = acc[i][j][rr] + bb;
        const size_t idx = (size_t)(r0 + rr) * N + c;
        if (EPI == 0)      outb[idx] = f2bf(v);
        else if (EPI == 1) atomicAdd(&outf[idx], v);
        else if (EPI == 2) outf[idx] = gelu_exact(v);
        else if (EPI == 3) outb[idx] = f2bf(bf2f(outb[idx]) * gelu_exact(v));
        else { if (f32w) outf[idx] = v; else outb[idx] = f2bf(v); }
      }
    }
  }
}

// ---------------- V transpose: Vt[h][d][j] ----------------
__global__ __launch_bounds__(256)
void vt_kernel(const u16* __restrict__ qkv, u16* __restrict__ Vt){
  const int h = blockIdx.x;
  const int t = threadIdx.x;
  const int d = t & 63;
  const int j0 = blockIdx.y * 32 + (t >> 6) * 8;
  u16 tmp[8];
  #pragma unroll
  for (int jj = 0; jj < 8; jj++)
    tmp[jj] = qkv[(size_t)(j0 + jj) * LDQKV + 2*E + h*64 + d];
  *(ushort4*)(Vt + (size_t)(h*64 + d) * L + j0)     = *(ushort4*)(tmp);
  *(ushort4*)(Vt + (size_t)(h*64 + d) * L + j0 + 4) = *(ushort4*)(tmp + 4);
}

// ---------------- MFMA flash attention, cooperative LDS staging, 64-key tiles ----------------
// Block: 4 waves = 64 Q rows; K/Vt tiles staged once per block (padded pitch 72 -> 2-way max).
#define KP 72
__global__ __launch_bounds__(256)
void attn_mfma(const u16* __restrict__ qkv, const u16* __restrict__ Vt,
               const float* __restrict__ padf, u16* __restrict__ outp){
  const int head = blockIdx.x;
  const int t = threadIdx.x;
  const int wave = t >> 6, lane = t & 63;
  const int col = lane & 15, quad = lane >> 4;
  const int q0 = blockIdx.y * 64 + wave * 16;

  __shared__ __align__(16) u16 Ks[64*KP];
  __shared__ __align__(16) u16 Vs[64*KP];
  __shared__ __align__(16) u16 Pb[4][16*KP];
  u16* P = Pb[wave];

  const float slope = exp2f(head < 8 ? -(float)(head+1) : -0.5f - (float)(head-8));
  const float scale = 0.125f;

  const u16* qrow = qkv + (size_t)(q0 + col) * LDQKV + head*64;
  const bf16x8 qf0 = *(const bf16x8*)(qrow + quad*8);
  const bf16x8 qf1 = *(const bf16x8*)(qrow + 32 + quad*8);

  const u16* kbase  = qkv + E + head*64;
  const u16* vtbase = Vt + (size_t)(head*64) * L;

  const int strow = t >> 2, stc = (t & 3) * 16;   // staging: 4 threads/row, 32B each

  float m_i[4] = {-1e30f,-1e30f,-1e30f,-1e30f};
  float l_i[4] = {0.f,0.f,0.f,0.f};
  f32x4 oacc[4];
  #pragma unroll
  for (int nt = 0; nt < 4; nt++) oacc[nt] = (f32x4){0.f,0.f,0.f,0.f};

  for (int kt = 0; kt < L; kt += 64){
    // ---- cooperative stage: K[64 keys][64 d], Vt[64 d][64 keys] ----
    const u16* kg = kbase + (size_t)(kt + strow) * LDQKV + stc;
    *(bf16x8*)(Ks + strow*KP + stc)     = *(const bf16x8*)(kg);
    *(bf16x8*)(Ks + strow*KP + stc + 8) = *(const bf16x8*)(kg + 8);
    const u16* vg = vtbase + (size_t)strow * L + kt + stc;
    *(bf16x8*)(Vs + strow*KP + stc)     = *(const bf16x8*)(vg);
    *(bf16x8*)(Vs + strow*KP + stc + 8) = *(const bf16x8*)(vg + 8);
    __syncthreads();

    // ---- QK^T: S[16q][64k] via 8 MFMAs ----
    f32x4 s[4];
    #pragma unroll
    for (int nt = 0; nt < 4; nt++){
      const u16* kr = Ks + (nt*16 + col)*KP;
      bf16x8 kf0 = *(const bf16x8*)(kr + quad*8);
      bf16x8 kf1 = *(const bf16x8*)(kr + 32 + quad*8);
      f32x4 z = (f32x4){0.f,0.f,0.f,0.f};
      z = MFMA_BF16(qf0, kf0, z);
      z = MFMA_BF16(qf1, kf1, z);
      s[nt] = z;
    }
    // ---- online softmax ----
    float padv[4];
    #pragma unroll
    for (int nt = 0; nt < 4; nt++) padv[nt] = padf[kt + nt*16 + col];
    float al[4];
    #pragma unroll
    for (int r = 0; r < 4; r++){
      const float ip = (float)(q0 + quad*4 + r);
      float sv[4]; float mx = -1e30f;
      #pragma unroll
      for (int nt = 0; nt < 4; nt++){
        sv[nt] = s[nt][r] * scale + slope * ((float)(kt + nt*16 + col) - ip) + padv[nt];
        mx = fmaxf(mx, sv[nt]);
      }
      mx = fmaxf(mx, __shfl_xor(mx, 1));
      mx = fmaxf(mx, __shfl_xor(mx, 2));
      mx = fmaxf(mx, __shfl_xor(mx, 4));
      mx = fmaxf(mx, __shfl_xor(mx, 8));
      const float mnew = fmaxf(m_i[r], mx);
      const float a = __expf(m_i[r] - mnew);
      m_i[r] = mnew; al[r] = a;
      float ps = 0.f;
      #pragma unroll
      for (int nt = 0; nt < 4; nt++){
        u16 e = f2bf(__expf(sv[nt] - mnew));
        P[(quad*4 + r)*KP + nt*16 + col] = e;
        ps += bf2f(e);
      }
      ps += __shfl_xor(ps, 1);
      ps += __shfl_xor(ps, 2);
      ps += __shfl_xor(ps, 4);
      ps += __shfl_xor(ps, 8);
      l_i[r] = l_i[r] * a + ps;
    }
    #pragma unroll
    for (int nt = 0; nt < 4; nt++)
      #pragma unroll
      for (int r = 0; r < 4; r++) oacc[nt][r] *= al[r];

    // ---- PV: O += P[16x64] @ V[64x64] via 8 MFMAs ----
    asm volatile("s_waitcnt lgkmcnt(0)" ::: "memory");
    const bf16x8 pa0 = *(const bf16x8*)(P + col*KP + quad*8);
    const bf16x8 pa1 = *(const bf16x8*)(P + col*KP + 32 + quad*8);
    #pragma unroll
    for (int nt = 0; nt < 4; nt++){
      const u16* vr = Vs + (nt*16 + col)*KP;
      const bf16x8 vb0 = *(const bf16x8*)(vr + quad*8);
      const bf16x8 vb1 = *(const bf16x8*)(vr + 32 + quad*8);
      oacc[nt] = MFMA_BF16(pa0, vb0, oacc[nt]);
      oacc[nt] = MFMA_BF16(pa1, vb1, oacc[nt]);
    }
    __syncthreads();   // Ks/Vs consumed; safe to restage
  }
  #pragma unroll
  for (int nt = 0; nt < 4; nt++)
    #pragma unroll
    for (int r = 0; r < 4; r++){
      const int row = q0 + quad*4 + r;
      outp[(size_t)row * E + head*64 + nt*16 + col] = f2bf(oacc[nt][r] / l_i[r]);
    }
}

extern "C" void kernel_launch(void* const* d_in, const int* in_sizes, int n_in,
                              void* d_out, int out_size, void* d_ws, size_t ws_size,
                              hipStream_t stream){
  const int* tokens = (const int*)d_in[0];
  const int* amask  = (const int*)d_in[1];

  // ---- ws: flag | padf | x f32 | hbuf bf16 | Vt bf16 | weight casts (~76.7 MB) ----
  unsigned int* flag = (unsigned int*)d_ws;
  float* padf = (float*)((char*)d_ws + 256);          // L f32 = 8 KB
  float* x   = padf + L;                              // f32 residual, 6.29 MB
  u16* hbuf  = (u16*)(x + (size_t)L*E);               // LN out bf16, 3.15 MB
  u16* vtb   = hbuf + (size_t)L*E;                    // V^T [NH][64][L], 3.15 MB
  u16* wc    = vtb + (size_t)NH*64*L;

  const size_t N_INW  = (size_t)NL*3*E*E;
  const size_t N_OUTW = (size_t)NL*E*E;
  const size_t N_FW1  = (size_t)NL*2*FFN*E;
  const size_t N_FW2  = (size_t)NL*E*FFN;
  const size_t N_MW1  = (size_t)E*E;
  const size_t N_MW2  = (size_t)VOC*E;
  u16* in_w  = wc;                 wc += N_INW;
  u16* out_w = wc;                 wc += N_OUTW;
  u16* ffw1  = wc;                 wc += N_FW1;
  u16* ffw2  = wc;                 wc += N_FW2;
  u16* mw1   = wc;                 wc += N_MW1;
  u16* mw2   = wc;                 wc += N_MW2;

  // ---- activations in d_out (high-water 16.8 MB) ----
  u16* qkvb  = (u16*)d_out;
  u16* attnb = (u16*)d_out + (size_t)L*LDQKV;
  u16* abuf  = (u16*)d_out;
  float* tbuf = (float*)d_out;

  detect_kernel<<<1, 256, 0, stream>>>((const u16*)d_in[2], flag);
  padf_kernel<<<L/256, 256, 0, stream>>>(amask, padf);
  cast4_kernel<<<(int)(N_INW/1024), 256, 0, stream>>>(d_in[5],  in_w,  (int)(N_INW/4),  flag);
  cast4_kernel<<<(int)(N_OUTW/1024),256, 0, stream>>>(d_in[7],  out_w, (int)(N_OUTW/4), flag);
  cast4_kernel<<<(int)(N_FW1/1024), 256, 0, stream>>>(d_in[11], ffw1,  (int)(N_FW1/4),  flag);
  cast4_kernel<<<(int)(N_FW2/1024), 256, 0, stream>>>(d_in[13], ffw2,  (int)(N_FW2/4),  flag);
  cast4_kernel<<<(int)(N_MW1/1024), 256, 0, stream>>>(d_in[17], mw1,   (int)(N_MW1/4),  flag);
  cast4_kernel<<<(int)(N_MW2/1024), 256, 0, stream>>>(d_in[21], mw2,   (int)(N_MW2/4),  flag);

  embed_kernel<<<L*E/256, 256, 0, stream>>>(tokens, d_in[2], flag, x);

  for (int ly = 0; ly < NL; ly++){
    ln_kernel<<<L/4, 256, 0, stream>>>(x, d_in[3], d_in[4],
        (size_t)ly*E, (size_t)ly*E, flag, hbuf);
    gemm_bt<0><<<dim3(3*E/128, L/128), 256, 0, stream>>>(hbuf, in_w + (size_t)ly*3*E*E,
        d_in[6], (size_t)ly*3*E, flag, qkvb, nullptr, L, 3*E, E);
    vt_kernel<<<dim3(NH, L/32), 256, 0, stream>>>(qkvb, vtb);
    attn_mfma<<<dim3(NH, L/64), 256, 0, stream>>>(qkvb, vtb, padf, attnb);
    gemm_bt<1><<<dim3(E/128, L/128, 2), 256, 0, stream>>>(attnb, out_w + (size_t)ly*E*E,
        d_in[8], (size_t)ly*E, flag, nullptr, x, L, E, E);
    ln_kernel<<<L/4, 256, 0, stream>>>(x, d_in[9], d_in[10],
        (size_t)ly*E, (size_t)ly*E, flag, hbuf);
    gemm_bt<0><<<dim3(FFN/128, L/128), 256, 0, stream>>>(hbuf,
        ffw1 + (size_t)ly*2*FFN*E, d_in[12], (size_t)ly*2*FFN, flag,
        abuf, nullptr, L, FFN, E);
    gemm_bt<3><<<dim3(FFN/128, L/128), 256, 0, stream>>>(hbuf,
        ffw1 + (size_t)ly*2*FFN*E + (size_t)FFN*E, d_in[12], (size_t)ly*2*FFN + FFN, flag,
        abuf, nullptr, L, FFN, E);
    gemm_bt<1><<<dim3(E/128, L/128, 2), 256, 0, stream>>>(abuf, ffw2 + (size_t)ly*E*FFN,
        d_in[14], (size_t)ly*E, flag, nullptr, x, L, E, FFN);
  }
  ln_kernel<<<L/4, 256, 0, stream>>>(x, d_in[15], d_in[16], 0, 0, flag, hbuf);
  gemm_bt<2><<<dim3(E/128, L/128), 256, 0, stream>>>(hbuf, mw1,
      d_in[18], 0, flag, nullptr, tbuf, L, E, E);
  ln_kernel<<<L/4, 256, 0, stream>>>(tbuf, d_in[19], d_in[20], 0, 0, flag, hbuf);
  gemm_bt<4><<<dim3(VOC/128, L/128), 256, 0, stream>>>(hbuf, mw2,
      d_in[22], 0, flag, (u16*)d_out, (float*)d_out, L, VOC, E);
}

// Round 9
// 1148.173 us; speedup vs baseline: 3.6079x; 1.0706x over previous
//
#include <hip/hip_runtime.h>
#include <math.h>
#include <cstdint>

#define L 2048
#define E 768
#define NH 12
#define NL 4
#define FFN 2048
#define VOC 4096
#define LDQKV (3*E)

typedef unsigned short u16;
typedef __bf16 bf16x8 __attribute__((ext_vector_type(8)));
typedef float f32x4 __attribute__((ext_vector_type(4)));

__device__ __forceinline__ float bf2f(u16 u){
  union { unsigned int i; float f; } v; v.i = ((unsigned int)u) << 16; return v.f;
}
__device__ __forceinline__ u16 f2bf(float f){
  union { float fl; unsigned int i; } v; v.fl = f;
  unsigned int r = v.i + 0x7fffu + ((v.i >> 16) & 1u);
  return (u16)(r >> 16);
}
__device__ __forceinline__ float gelu_exact(float x){
  return 0.5f * x * (1.0f + erff(x * 0.70710678118654752f));
}
__device__ __forceinline__ float ldw(const void* p, size_t i, int f32w){
  return f32w ? ((const float*)p)[i] : bf2f(((const u16*)p)[i]);
}

#define MFMA_BF16(a,b,c) __builtin_amdgcn_mfma_f32_16x16x32_bf16(a,b,c,0,0,0)

// async global->LDS, 16B/lane; LDS dest = wave-uniform base + lane*16 (m97/m104)
__device__ __forceinline__ void gload16(const u16* g, const u16* l){
  __builtin_amdgcn_global_load_lds(
      (__attribute__((address_space(1))) void*)(uintptr_t)(const void*)g,
      (__attribute__((address_space(3))) void*)(unsigned int)(uintptr_t)(const void*)l,
      16, 0, 0);
}

// ---------------- dtype detect ----------------
__global__ __launch_bounds__(256) void detect_kernel(const u16* __restrict__ emb,
                                                     unsigned int* __restrict__ flag){
  __shared__ int s;
  if (threadIdx.x == 0) s = 0;
  __syncthreads();
  float mx = 0.f;
  for (int i = threadIdx.x; i < 16384; i += 256)
    mx = fmaxf(mx, fabsf(bf2f(emb[2*i])));
  if (mx > 1e4f) s = 1;
  __syncthreads();
  if (threadIdx.x == 0) *flag = (unsigned int)s;
}

// ---------------- weight cast -> canonical bf16 ----------------
__global__ __launch_bounds__(256) void cast4_kernel(const void* __restrict__ src,
                                                    u16* __restrict__ dst, int n4,
                                                    const unsigned int* __restrict__ flag){
  int i4 = blockIdx.x * 256 + threadIdx.x;
  if (i4 >= n4) return;
  size_t i = (size_t)i4 * 4;
  ushort4 o;
  if (*flag){
    const float4 f = ((const float4*)src)[i4];
    o.x = f2bf(f.x); o.y = f2bf(f.y); o.z = f2bf(f.z); o.w = f2bf(f.w);
  } else {
    o = ((const ushort4*)src)[i4];
  }
  *(ushort4*)(dst + i) = o;
}

// ---------------- key-pad float mask precompute ----------------
__global__ __launch_bounds__(256) void padf_kernel(const int* __restrict__ amask,
                                                   float* __restrict__ padf){
  int i = blockIdx.x * 256 + threadIdx.x;
  padf[i] = (amask[i] == 0) ? 1.0f : 0.0f;   // reference adds FLOAT mask
}

// ---------------- embedding gather -> f32 residual ----------------
__global__ __launch_bounds__(256) void embed_kernel(const int* __restrict__ tok,
                                                    const void* __restrict__ emb,
                                                    const unsigned int* __restrict__ flag,
                                                    float* __restrict__ x){
  const int f32w = (int)*flag;
  int idx = blockIdx.x * 256 + threadIdx.x;
  int l = idx / E, e = idx - l * E;
  x[idx] = ldw(emb, (size_t)tok[l] * E + e, f32w);
}

// ---------------- LayerNorm: f32 in, bf16 out ----------------
__global__ __launch_bounds__(256) void ln_kernel(const float* __restrict__ x,
                                                 const void* __restrict__ g,
                                                 const void* __restrict__ b,
                                                 size_t goff, size_t boff,
                                                 const unsigned int* __restrict__ flag,
                                                 u16* __restrict__ o){
  const int f32w = (int)*flag;
  const int wave = threadIdx.x >> 6, lane = threadIdx.x & 63;
  const int row = blockIdx.x * 4 + wave;
  const float* xr = x + (size_t)row * E;
  float v[12]; float s = 0.f;
  #pragma unroll
  for (int i = 0; i < 12; i++){ v[i] = xr[lane + i*64]; s += v[i]; }
  #pragma unroll
  for (int off = 32; off > 0; off >>= 1) s += __shfl_xor(s, off);
  const float mean = s * (1.0f / E);
  float vs = 0.f;
  #pragma unroll
  for (int i = 0; i < 12; i++){ float d = v[i] - mean; vs += d * d; }
  #pragma unroll
  for (int off = 32; off > 0; off >>= 1) vs += __shfl_xor(vs, off);
  const float rstd = rsqrtf(vs * (1.0f / E) + 1e-5f);
  u16* orow = o + (size_t)row * E;
  #pragma unroll
  for (int i = 0; i < 12; i++){
    int c = lane + i*64;
    orow[c] = f2bf((v[i] - mean) * rstd * ldw(g, goff + c, f32w) + ldw(b, boff + c, f32w));
  }
}

// ---------------- MFMA GEMM, software-pipelined (AITER-style) ----------------
// Double-buffered LDS; prefetch tile k+1 via global_load_lds; raw s_barrier with
// s_waitcnt vmcnt(4) (prefetch stays in flight across barrier) + lgkmcnt(0) only.
// EPI 0: bf16 store | 1: f32 atomicAdd residual | 2: f32 gelu | 3: bf16 in-place *= gelu | 4: final (flag? f32 : bf16)
template<int EPI>
__global__ __launch_bounds__(256)
void gemm_bt(const u16* __restrict__ A, const u16* __restrict__ Bm,
             const void* __restrict__ bias, size_t biasoff,
             const unsigned int* __restrict__ flag,
             u16* __restrict__ outb, float* __restrict__ outf,
             int M, int N, int K){
  __shared__ __align__(16) u16 As[2*128*32];
  __shared__ __align__(16) u16 Bs[2*128*32];
  const int t = threadIdx.x;
  const int lane = t & 63;
  const int col = lane & 15, quad = lane >> 4;
  const int wave = t >> 6;
  const int wr = (wave >> 1) * 64, wc = (wave & 1) * 64;
  const int row0 = blockIdx.y * 128, col0 = blockIdx.x * 128;
  const int f32w = (int)*flag;

  int kb = 0, ke = K;
  if (gridDim.z > 1){ const int kc = K / (int)gridDim.z; kb = blockIdx.z * kc; ke = kb + kc; }

  const int sr = t >> 2;            // staging map: 4 lanes/row, 8 u16 (16B) each
  const int sc = (t & 3) * 8;
  const u16* Ag = A + (size_t)(row0 + sr) * K + sc;
  const u16* Bg = Bm + (size_t)(col0 + sr) * K + sc;

  f32x4 acc[4][4];
  #pragma unroll
  for (int i = 0; i < 4; i++)
    #pragma unroll
    for (int j = 0; j < 4; j++) acc[i][j] = (f32x4){0.f,0.f,0.f,0.f};

  // prologue: stage tile 0 into buffer 0
  gload16(Ag + kb,                As + wave*512);
  gload16(Ag + (size_t)64*K + kb, As + wave*512 + 2048);
  gload16(Bg + kb,                Bs + wave*512);
  gload16(Bg + (size_t)64*K + kb, Bs + wave*512 + 2048);

  int p = 0;
  for (int k0 = kb; k0 < ke; k0 += 32, p ^= 1){
    if (k0 + 32 < ke){
      const int nx = (p ^ 1) * 4096;
      gload16(Ag + k0 + 32,                As + nx + wave*512);
      gload16(Ag + (size_t)64*K + k0 + 32, As + nx + wave*512 + 2048);
      gload16(Bg + k0 + 32,                Bs + nx + wave*512);
      gload16(Bg + (size_t)64*K + k0 + 32, Bs + nx + wave*512 + 2048);
      // wait only the 4 older loads (current tile); 4 prefetch stay in flight
      asm volatile("s_waitcnt vmcnt(4)\n\ts_barrier" ::: "memory");
    } else {
      asm volatile("s_waitcnt vmcnt(0)\n\ts_barrier" ::: "memory");
    }
    const u16* Ab = As + p*4096;
    const u16* Bb = Bs + p*4096;
    bf16x8 af[4], bfr[4];
    #pragma unroll
    for (int i = 0; i < 4; i++)
      af[i] = *(const bf16x8*)(Ab + (wr + i*16 + col)*32 + quad*8);
    #pragma unroll
    for (int j = 0; j < 4; j++)
      bfr[j] = *(const bf16x8*)(Bb + (wc + j*16 + col)*32 + quad*8);
    #pragma unroll
    for (int i = 0; i < 4; i++)
      #pragma unroll
      for (int j = 0; j < 4; j++)
        acc[i][j] = MFMA_BF16(af[i], bfr[j], acc[i][j]);
    // ds_reads complete (lgkm) before crossing; vmcnt (prefetch) NOT drained
    asm volatile("s_waitcnt lgkmcnt(0)\n\ts_barrier" ::: "memory");
  }

  #pragma unroll
  for (int j = 0; j < 4; j++){
    const int c = col0 + wc + j*16 + col;
    const float bb = (gridDim.z > 1 && blockIdx.z != 0) ? 0.f : ldw(bias, biasoff + c, f32w);
    #pragma unroll
    for (int i = 0; i < 4; i++){
      const int r0 = row0 + wr + i*16 + quad*4;
      #pragma unroll
      for (int rr = 0; rr < 4; rr++){
        const float v = acc[i][j][rr] + bb;
        const size_t idx = (size_t)(r0 + rr) * N + c;
        if (EPI == 0)      outb[idx] = f2bf(v);
        else if (EPI == 1) atomicAdd(&outf[idx], v);
        else if (EPI == 2) outf[idx] = gelu_exact(v);
        else if (EPI == 3) outb[idx] = f2bf(bf2f(outb[idx]) * gelu_exact(v));
        else { if (f32w) outf[idx] = v; else outb[idx] = f2bf(v); }
      }
    }
  }
}

// ---------------- V transpose: Vt[h][d][j] ----------------
__global__ __launch_bounds__(256)
void vt_kernel(const u16* __restrict__ qkv, u16* __restrict__ Vt){
  const int h = blockIdx.x;
  const int t = threadIdx.x;
  const int d = t & 63;
  const int j0 = blockIdx.y * 32 + (t >> 6) * 8;
  u16 tmp[8];
  #pragma unroll
  for (int jj = 0; jj < 8; jj++)
    tmp[jj] = qkv[(size_t)(j0 + jj) * LDQKV + 2*E + h*64 + d];
  *(ushort4*)(Vt + (size_t)(h*64 + d) * L + j0)     = *(ushort4*)(tmp);
  *(ushort4*)(Vt + (size_t)(h*64 + d) * L + j0 + 4) = *(ushort4*)(tmp + 4);
}

// ---------------- MFMA flash attention: fragment-contiguous LDS, reg-dbuf staging ----------------
// LDS layout (K,V,P): frag[(chunk)*16 + col]*8 + j  -> every b128 read is lane*16B (conflict-free).
__global__ __launch_bounds__(256)
void attn_mfma(const u16* __restrict__ qkv, const u16* __restrict__ Vt,
               const float* __restrict__ padf, u16* __restrict__ outp){
  const int head = blockIdx.x;
  const int t = threadIdx.x;
  const int wave = t >> 6, lane = t & 63;
  const int col = lane & 15, quad = lane >> 4;
  const int q0 = blockIdx.y * 64 + wave * 16;

  __shared__ __align__(16) u16 Kf[64*64];      // [nt*8+c][col][8]
  __shared__ __align__(16) u16 Vf[64*64];
  __shared__ __align__(16) u16 Pf[4][16*64];   // per wave: [c][m][8]
  u16* P = Pf[wave];

  const float slope = exp2f(head < 8 ? -(float)(head+1) : -0.5f - (float)(head-8));
  const float scale = 0.125f;

  const u16* qrow = qkv + (size_t)(q0 + col) * LDQKV + head*64;
  const bf16x8 qf0 = *(const bf16x8*)(qrow + quad*8);
  const bf16x8 qf1 = *(const bf16x8*)(qrow + 32 + quad*8);

  const u16* kbase  = qkv + E + head*64;
  const u16* vtbase = Vt + (size_t)(head*64) * L;

  const int skey = t >> 2;             // K: key row / V: d row
  const int stc  = (t & 3) * 16;       // 32B chunk-pair offset
  const int kw0  = (((skey >> 4)*8 + (t & 3)*2)*16 + (skey & 15))*8;   // frag-order write
  const int kw1  = kw0 + 128;

  float m_i[4] = {-1e30f,-1e30f,-1e30f,-1e30f};
  float l_i[4] = {0.f,0.f,0.f,0.f};
  f32x4 oacc[4];
  #pragma unroll
  for (int nt = 0; nt < 4; nt++) oacc[nt] = (f32x4){0.f,0.f,0.f,0.f};

  // preload tile 0 into regs
  const u16* kg = kbase + (size_t)skey * LDQKV + stc;
  const u16* vg = vtbase + (size_t)skey * L + stc;
  bf16x8 kr0 = *(const bf16x8*)(kg), kr1 = *(const bf16x8*)(kg + 8);
  bf16x8 vr0 = *(const bf16x8*)(vg), vr1 = *(const bf16x8*)(vg + 8);

  for (int kt = 0; kt < L; kt += 64){
    // stage current tile (fragment order; 2-way write aliasing = free)
    *(bf16x8*)(Kf + kw0) = kr0;
    *(bf16x8*)(Kf + kw1) = kr1;
    *(bf16x8*)(Vf + kw0) = vr0;
    *(bf16x8*)(Vf + kw1) = vr1;
    asm volatile("s_waitcnt lgkmcnt(0)\n\ts_barrier" ::: "memory");
    // prefetch next tile into regs (latency overlaps compute below)
    if (kt + 64 < L){
      const u16* kg2 = kbase + (size_t)(kt + 64 + skey) * LDQKV + stc;
      const u16* vg2 = vtbase + (size_t)skey * L + kt + 64 + stc;
      kr0 = *(const bf16x8*)(kg2); kr1 = *(const bf16x8*)(kg2 + 8);
      vr0 = *(const bf16x8*)(vg2); vr1 = *(const bf16x8*)(vg2 + 8);
    }

    // ---- QK^T: S[16q][64k], 8 MFMAs, conflict-free lane*16B reads ----
    f32x4 s[4];
    #pragma unroll
    for (int nt = 0; nt < 4; nt++){
      bf16x8 kf0 = *(const bf16x8*)(Kf + nt*1024 + lane*8);
      bf16x8 kf1 = *(const bf16x8*)(Kf + nt*1024 + 512 + lane*8);
      f32x4 z = (f32x4){0.f,0.f,0.f,0.f};
      z = MFMA_BF16(qf0, kf0, z);
      z = MFMA_BF16(qf1, kf1, z);
      s[nt] = z;
    }
    // ---- online softmax ----
    float padv[4];
    #pragma unroll
    for (int nt = 0; nt < 4; nt++) padv[nt] = padf[kt + nt*16 + col];
    float al[4];
    #pragma unroll
    for (int r = 0; r < 4; r++){
      const float ip = (float)(q0 + quad*4 + r);
      float sv[4]; float mx = -1e30f;
      #pragma unroll
      for (int nt = 0; nt < 4; nt++){
        sv[nt] = s[nt][r] * scale + slope * ((float)(kt + nt*16 + col) - ip) + padv[nt];
        mx = fmaxf(mx, sv[nt]);
      }
      mx = fmaxf(mx, __shfl_xor(mx, 1));
      mx = fmaxf(mx, __shfl_xor(mx, 2));
      mx = fmaxf(mx, __shfl_xor(mx, 4));
      mx = fmaxf(mx, __shfl_xor(mx, 8));
      const float mnew = fmaxf(m_i[r], mx);
      const float a = __expf(m_i[r] - mnew);
      m_i[r] = mnew; al[r] = a;
      float ps = 0.f;
      #pragma unroll
      for (int nt = 0; nt < 4; nt++){
        u16 e = f2bf(__expf(sv[nt] - mnew));
        // P[m=quad*4+r][k=nt*16+col] in fragment order
        P[((nt*2 + (col >> 3))*16 + quad*4 + r)*8 + (col & 7)] = e;
        ps += bf2f(e);
      }
      ps += __shfl_xor(ps, 1);
      ps += __shfl_xor(ps, 2);
      ps += __shfl_xor(ps, 4);
      ps += __shfl_xor(ps, 8);
      l_i[r] = l_i[r] * a + ps;
    }
    #pragma unroll
    for (int nt = 0; nt < 4; nt++)
      #pragma unroll
      for (int r = 0; r < 4; r++) oacc[nt][r] *= al[r];

    // ---- PV: O += P[16x64] @ V[64x64], 8 MFMAs ----
    asm volatile("s_waitcnt lgkmcnt(0)" ::: "memory");
    const bf16x8 pa0 = *(const bf16x8*)(P + lane*8);
    const bf16x8 pa1 = *(const bf16x8*)(P + 512 + lane*8);
    #pragma unroll
    for (int nt = 0; nt < 4; nt++){
      const bf16x8 vb0 = *(const bf16x8*)(Vf + nt*1024 + lane*8);
      const bf16x8 vb1 = *(const bf16x8*)(Vf + nt*1024 + 512 + lane*8);
      oacc[nt] = MFMA_BF16(pa0, vb0, oacc[nt]);
      oacc[nt] = MFMA_BF16(pa1, vb1, oacc[nt]);
    }
    // reads done before restage; do NOT drain vmcnt (reg prefetch in flight)
    asm volatile("s_waitcnt lgkmcnt(0)\n\ts_barrier" ::: "memory");
  }
  #pragma unroll
  for (int nt = 0; nt < 4; nt++)
    #pragma unroll
    for (int r = 0; r < 4; r++){
      const int row = q0 + quad*4 + r;
      outp[(size_t)row * E + head*64 + nt*16 + col] = f2bf(oacc[nt][r] / l_i[r]);
    }
}

extern "C" void kernel_launch(void* const* d_in, const int* in_sizes, int n_in,
                              void* d_out, int out_size, void* d_ws, size_t ws_size,
                              hipStream_t stream){
  const int* tokens = (const int*)d_in[0];
  const int* amask  = (const int*)d_in[1];

  // ---- ws: flag | padf | x f32 | hbuf bf16 | Vt bf16 | weight casts (~76.7 MB) ----
  unsigned int* flag = (unsigned int*)d_ws;
  float* padf = (float*)((char*)d_ws + 256);
  float* x   = padf + L;
  u16* hbuf  = (u16*)(x + (size_t)L*E);
  u16* vtb   = hbuf + (size_t)L*E;
  u16* wc    = vtb + (size_t)NH*64*L;

  const size_t N_INW  = (size_t)NL*3*E*E;
  const size_t N_OUTW = (size_t)NL*E*E;
  const size_t N_FW1  = (size_t)NL*2*FFN*E;
  const size_t N_FW2  = (size_t)NL*E*FFN;
  const size_t N_MW1  = (size_t)E*E;
  const size_t N_MW2  = (size_t)VOC*E;
  u16* in_w  = wc;                 wc += N_INW;
  u16* out_w = wc;                 wc += N_OUTW;
  u16* ffw1  = wc;                 wc += N_FW1;
  u16* ffw2  = wc;                 wc += N_FW2;
  u16* mw1   = wc;                 wc += N_MW1;
  u16* mw2   = wc;                 wc += N_MW2;

  // ---- activations in d_out (high-water 16.8 MB) ----
  u16* qkvb  = (u16*)d_out;
  u16* attnb = (u16*)d_out + (size_t)L*LDQKV;
  u16* abuf  = (u16*)d_out;
  float* tbuf = (float*)d_out;

  detect_kernel<<<1, 256, 0, stream>>>((const u16*)d_in[2], flag);
  padf_kernel<<<L/256, 256, 0, stream>>>(amask, padf);
  cast4_kernel<<<(int)(N_INW/1024), 256, 0, stream>>>(d_in[5],  in_w,  (int)(N_INW/4),  flag);
  cast4_kernel<<<(int)(N_OUTW/1024),256, 0, stream>>>(d_in[7],  out_w, (int)(N_OUTW/4), flag);
  cast4_kernel<<<(int)(N_FW1/1024), 256, 0, stream>>>(d_in[11], ffw1,  (int)(N_FW1/4),  flag);
  cast4_kernel<<<(int)(N_FW2/1024), 256, 0, stream>>>(d_in[13], ffw2,  (int)(N_FW2/4),  flag);
  cast4_kernel<<<(int)(N_MW1/1024), 256, 0, stream>>>(d_in[17], mw1,   (int)(N_MW1/4),  flag);
  cast4_kernel<<<(int)(N_MW2/1024), 256, 0, stream>>>(d_in[21], mw2,   (int)(N_MW2/4),  flag);

  embed_kernel<<<L*E/256, 256, 0, stream>>>(tokens, d_in[2], flag, x);

  for (int ly = 0; ly < NL; ly++){
    ln_kernel<<<L/4, 256, 0, stream>>>(x, d_in[3], d_in[4],
        (size_t)ly*E, (size_t)ly*E, flag, hbuf);
    gemm_bt<0><<<dim3(3*E/128, L/128), 256, 0, stream>>>(hbuf, in_w + (size_t)ly*3*E*E,
        d_in[6], (size_t)ly*3*E, flag, qkvb, nullptr, L, 3*E, E);
    vt_kernel<<<dim3(NH, L/32), 256, 0, stream>>>(qkvb, vtb);
    attn_mfma<<<dim3(NH, L/64), 256, 0, stream>>>(qkvb, vtb, padf, attnb);
    gemm_bt<1><<<dim3(E/128, L/128, 2), 256, 0, stream>>>(attnb, out_w + (size_t)ly*E*E,
        d_in[8], (size_t)ly*E, flag, nullptr, x, L, E, E);
    ln_kernel<<<L/4, 256, 0, stream>>>(x, d_in[9], d_in[10],
        (size_t)ly*E, (size_t)ly*E, flag, hbuf);
    gemm_bt<0><<<dim3(FFN/128, L/128), 256, 0, stream>>>(hbuf,
        ffw1 + (size_t)ly*2*FFN*E, d_in[12], (size_t)ly*2*FFN, flag,
        abuf, nullptr, L, FFN, E);
    gemm_bt<3><<<dim3(FFN/128, L/128), 256, 0, stream>>>(hbuf,
        ffw1 + (size_t)ly*2*FFN*E + (size_t)FFN*E, d_in[12], (size_t)ly*2*FFN + FFN, flag,
        abuf, nullptr, L, FFN, E);
    gemm_bt<1><<<dim3(E/128, L/128, 2), 256, 0, stream>>>(abuf, ffw2 + (size_t)ly*E*FFN,
        d_in[14], (size_t)ly*E, flag, nullptr, x, L, E, FFN);
  }
  ln_kernel<<<L/4, 256, 0, stream>>>(x, d_in[15], d_in[16], 0, 0, flag, hbuf);
  gemm_bt<2><<<dim3(E/128, L/128), 256, 0, stream>>>(hbuf, mw1,
      d_in[18], 0, flag, nullptr, tbuf, L, E, E);
  ln_kernel<<<L/4, 256, 0, stream>>>(tbuf, d_in[19], d_in[20], 0, 0, flag, hbuf);
  gemm_bt<4><<<dim3(VOC/128, L/128), 256, 0, stream>>>(hbuf, mw2,
      d_in[22], 0, flag, (u16*)d_out, (float*)d_out, L, VOC, E);
}